// Round 24
// baseline (203.468 us; speedup 1.0000x reference)
//
#include <hip/hip_runtime.h>

#define L 2048
#define D 2048
#define NH 16
#define HD 128

typedef __attribute__((ext_vector_type(8))) _Float16 half8;
typedef __attribute__((ext_vector_type(4))) float f32x4;

__device__ __forceinline__ void gload_lds16(const void* g, void* l) {
    __builtin_amdgcn_global_load_lds(
        (const __attribute__((address_space(1))) uint32_t*)g,
        (__attribute__((address_space(3))) uint32_t*)l, 16, 0, 0);
}

// pack two f32 -> fp16x2 (RTZ), return as u32
__device__ __forceinline__ unsigned pkrtz_u32(float a, float b) {
    union { __fp16 __attribute__((ext_vector_type(2))) h; unsigned u; } c;
    c.h = __builtin_amdgcn_cvt_pkrtz(a, b);
    return c.u;
}

// ---------------- fused f32 -> fp16 convert of x, W_qkv, W_out ----------------
__global__ void cvt3_kernel(const float* __restrict__ a, const float* __restrict__ b,
                            const float* __restrict__ c, _Float16* __restrict__ oa,
                            _Float16* __restrict__ ob, _Float16* __restrict__ oc,
                            int na, int nb, int nc) {
    int idx = blockIdx.x * blockDim.x + threadIdx.x;
    int stride = gridDim.x * blockDim.x;
    int ntot = na + nb + nc;
    for (int i = idx; i < ntot; i += stride) {
        const float* src; _Float16* dst; int j;
        if (i < na)            { src = a; dst = oa; j = i; }
        else if (i < na + nb)  { src = b; dst = ob; j = i - na; }
        else                   { src = c; dst = oc; j = i - na - nb; }
        float4 v = reinterpret_cast<const float4*>(src)[j];
        union { _Float16 h[4]; uint2 u; } pk;
        pk.h[0] = (_Float16)v.x; pk.h[1] = (_Float16)v.y;
        pk.h[2] = (_Float16)v.z; pk.h[3] = (_Float16)v.w;
        reinterpret_cast<uint2*>(dst)[j] = pk.u;
    }
}

// ---------------- QKV GEMM, v3: 128x64 tile for 6 blocks/CU ----------------
// r23 theory: the 2-barrier drain structure's stall is hidden by CO-RESIDENT
// blocks (m114); gemm ran ~3/CU. r17 measured the same change direction on
// gemm_out (64x128 @ 2/CU beat 128^2 @ 1/CU). v3: 128x64 tile, grid (16,96)
// = 1536 blocks, LDS 24KB -> up to 6 blocks/CU. Loop is a clone of the
// PROVEN gemm_out structure (A/B roles swapped): 4 waves 2Mx2N, wave tile
// 64x32, acc[4][2], BK=32, stage = 3 DMAs/thread (A 2, B 1).
// Epilogue scatter unchanged: q linear; k d^((l&7)<<3); v l^((d&7)<<3).
__global__ __launch_bounds__(256) void gemm_qkv(
    const _Float16* __restrict__ A, const _Float16* __restrict__ B,
    _Float16* __restrict__ qk, _Float16* __restrict__ vt,
    int M, int N, int K)
{
    __shared__ __align__(16) _Float16 Asm[2][128 * 32];   // 2 x 8 KB
    __shared__ __align__(16) _Float16 Bsm[2][64 * 32];    // 2 x 4 KB
    int tid = threadIdx.x;
    int wid = tid >> 6;
    int lane = tid & 63;
    int wr = wid >> 1, wc = wid & 1;
    int m0 = blockIdx.x * 128;
    int n0 = blockIdx.y * 64;
    int lr = lane & 15;
    int lg = lane >> 4;

    const char* Asrc = (const char*)(A + (size_t)(m0 + (tid >> 2)) * K) + (tid & 3) * 16;
    const char* Bsrc = (const char*)(B + (size_t)(n0 + (tid >> 2)) * K) + (tid & 3) * 16;
    size_t rowskip = (size_t)64 * K * 2;   // 64 source rows, bytes

    auto stage = [&](int k0, int b) {
        const char* as = Asrc + (size_t)k0 * 2;
        const char* bs = Bsrc + (size_t)k0 * 2;
        char* ad = (char*)&Asm[b][0] + wid * 1024;   // + lane*16 by hardware
        char* bd = (char*)&Bsm[b][0] + wid * 1024;
        gload_lds16(as, ad);                  // A rows 0..63
        gload_lds16(as + rowskip, ad + 4096); // A rows 64..127
        gload_lds16(bs, bd);                  // B rows 0..63
    };

    f32x4 acc[4][2];
#pragma unroll
    for (int i = 0; i < 4; i++)
#pragma unroll
        for (int j = 0; j < 2; j++)
            acc[i][j] = (f32x4){0.f, 0.f, 0.f, 0.f};

    int NT = K / 32;
    stage(0, 0);
    asm volatile("s_waitcnt vmcnt(0)" ::: "memory");
    __syncthreads();

    for (int t = 0; t < NT; t++) {
        int cur = t & 1;
        if (t + 1 < NT) stage((t + 1) * 32, cur ^ 1);

        const char* ab = (const char*)&Asm[cur][0] + (wr * 64 + lr) * 64 + lg * 16;
        const char* bb = (const char*)&Bsm[cur][0] + (wc * 32 + lr) * 64 + lg * 16;
        half8 a[4], b[2];
#pragma unroll
        for (int i = 0; i < 4; i++) a[i] = *(const half8*)(ab + i * 1024);
#pragma unroll
        for (int j = 0; j < 2; j++) b[j] = *(const half8*)(bb + j * 1024);
#pragma unroll
        for (int i = 0; i < 4; i++)
#pragma unroll
            for (int j = 0; j < 2; j++)
                acc[i][j] = __builtin_amdgcn_mfma_f32_16x16x32_f16(a[i], b[j], acc[i][j], 0, 0, 0);

        asm volatile("s_waitcnt vmcnt(0)" ::: "memory");
        __syncthreads();
    }

#pragma unroll
    for (int i = 0; i < 4; i++) {
#pragma unroll
        for (int j = 0; j < 2; j++) {
#pragma unroll
            for (int r = 0; r < 4; r++) {
                int row = m0 + wr * 64 + i * 16 + lg * 4 + r;  // C layout: row=(lane>>4)*4+reg
                int col = n0 + wc * 32 + j * 16 + lr;          //           col=lane&15
                float v = acc[i][j][r];
                int ts = col >> 11;
                int w2 = col & 2047;
                int h = w2 >> 7, d = w2 & 127;
                if (ts == 0) {
                    qk[(((size_t)h) * L + row) * HD + d] = (_Float16)v;
                } else if (ts == 1) {
                    int dsw = d ^ ((row & 7) << 3);
                    qk[(((size_t)NH + h) * L + row) * HD + dsw] = (_Float16)v;
                } else {
                    int lsw = row ^ ((d & 7) << 3);
                    vt[((size_t)h * HD + d) * L + lsw] = (_Float16)v;
                }
            }
        }
    }
}

// ---------------- output-projection GEMM ----------------
// 64x128 tile -> 512 blocks = 2 blocks/CU (r17: helped vs 1/CU).
__global__ __launch_bounds__(256) void gemm_out(
    const _Float16* __restrict__ A, const _Float16* __restrict__ B,
    float* __restrict__ Cout, int M, int N, int K)
{
    __shared__ __align__(16) _Float16 Asm[2][64 * 32];
    __shared__ __align__(16) _Float16 Bsm[2][128 * 32];
    int tid = threadIdx.x;
    int wid = tid >> 6;
    int lane = tid & 63;
    int m0 = blockIdx.x * 64;
    int n0 = blockIdx.y * 128;
    int lr = lane & 15;
    int lg = lane >> 4;

    const char* Asrc = (const char*)(A + (size_t)(m0 + (tid >> 2)) * K) + (tid & 3) * 16;
    const char* Bsrc = (const char*)(B + (size_t)(n0 + (tid >> 2)) * K) + (tid & 3) * 16;
    size_t rowskip = (size_t)64 * K * 2;

    auto stage = [&](int k0, int b) {
        const char* as = Asrc + (size_t)k0 * 2;
        const char* bs = Bsrc + (size_t)k0 * 2;
        char* ad = (char*)&Asm[b][0] + wid * 1024;
        char* bd = (char*)&Bsm[b][0] + wid * 1024;
        gload_lds16(as, ad);
        gload_lds16(bs, bd);
        gload_lds16(bs + rowskip, bd + 4096);
    };

    f32x4 acc[4][2];
#pragma unroll
    for (int i = 0; i < 4; i++)
#pragma unroll
        for (int j = 0; j < 2; j++)
            acc[i][j] = (f32x4){0.f, 0.f, 0.f, 0.f};

    int NT = K / 32;
    stage(0, 0);
    asm volatile("s_waitcnt vmcnt(0)" ::: "memory");
    __syncthreads();

    for (int t = 0; t < NT; t++) {
        int cur = t & 1;
        if (t + 1 < NT) stage((t + 1) * 32, cur ^ 1);

        const char* ab = (const char*)&Asm[cur][0] + lr * 64 + lg * 16;
        const char* bb = (const char*)&Bsm[cur][0] + (wid * 32 + lr) * 64 + lg * 16;
        half8 a[4], b[2];
#pragma unroll
        for (int i = 0; i < 4; i++) a[i] = *(const half8*)(ab + i * 1024);
#pragma unroll
        for (int j = 0; j < 2; j++) b[j] = *(const half8*)(bb + j * 1024);
#pragma unroll
        for (int i = 0; i < 4; i++)
#pragma unroll
            for (int j = 0; j < 2; j++)
                acc[i][j] = __builtin_amdgcn_mfma_f32_16x16x32_f16(a[i], b[j], acc[i][j], 0, 0, 0);

        asm volatile("s_waitcnt vmcnt(0)" ::: "memory");
        __syncthreads();
    }

#pragma unroll
    for (int i = 0; i < 4; i++) {
#pragma unroll
        for (int j = 0; j < 2; j++) {
#pragma unroll
            for (int r = 0; r < 4; r++) {
                int row = m0 + i * 16 + lg * 4 + r;
                int col = n0 + wid * 32 + j * 16 + lr;
                Cout[(size_t)row * N + col] = acc[i][j][r];
            }
        }
    }
}

// ---------------- fused RMSNorm + RoPE, v2: vectorized (G13) ----------------
__global__ void norm_rope(_Float16* __restrict__ qk) {
    int row = blockIdx.x * 16 + (threadIdx.x >> 4);   // 0 .. 2*NH*L-1
    int lane16 = threadIdx.x & 15;
    int l = row & (L - 1);
    int th = row >> 11;                  // t*NH + h, 0..31
    _Float16* p = qk + ((size_t)th * L + l) * HD + lane16 * 8;
    half8 v = *reinterpret_cast<const half8*>(p);
    float f[8];
    float ss = 0.f;
#pragma unroll
    for (int j = 0; j < 8; j++) { f[j] = (float)v[j]; ss += f[j] * f[j]; }
#pragma unroll
    for (int off = 1; off < 16; off <<= 1) ss += __shfl_xor(ss, off);
    float rinv = rsqrtf(ss * (1.0f / 128.0f) + 1e-5f);

    int dbase = (th >= NH) ? ((lane16 * 8) ^ ((l & 7) << 3)) : (lane16 * 8);
    int p0 = dbase >> 1;                 // first pair index of this lane's block
    half8 o;
#pragma unroll
    for (int k = 0; k < 4; k++) {
        float e = f[2 * k] * rinv;       // t_even (d = 2p)
        float od = f[2 * k + 1] * rinv;  // t_odd  (d = 2p+1)
        float freq = __expf(-0.17988946f * (float)(p0 + k));   // 2*ln(1e5)/128
        float sv, cv;
        __sincosf((float)l * freq, &sv, &cv);
        o[2 * k] = (_Float16)(od * cv - e * sv);
        o[2 * k + 1] = (_Float16)(od * sv + e * cv);
    }
    *reinterpret_cast<half8*>(p) = o;
}

// ---------------- causal flash attention, v15 (r21-exact) ----------------
__global__ __launch_bounds__(256, 2) void attn_kernel(
    const _Float16* __restrict__ qk, const _Float16* __restrict__ vt,
    _Float16* __restrict__ Oq, float* __restrict__ Lq)
{
    __shared__ __align__(16) _Float16 Kt[2][64 * HD];     // 2 x 16 KB
    __shared__ __align__(16) _Float16 Vt[2][64 * HD];     // 2 x 16 KB
    int wid = threadIdx.x >> 6, lane = threadIdx.x & 63;
    int lr = lane & 15, lg = lane >> 4;

    const float scale = 0.08838834764831845f;  // 1/sqrt(128)
    const float OFF = 4.0f;                    // static exp offset (absolute)

    int item = blockIdx.x;
    int qt = 15 - (item >> 6);
    int h = (item >> 2) & 15;
    int p = item & 3;
    int ntt = 2 * qt + 2;
    int per = (ntt + 3) >> 2;
    int t0 = p * per;
    int t1 = t0 + per < ntt ? t0 + per : ntt;
    int q0 = qt * 128 + wid * 32;
    int qa0 = q0 + lr;
    int qa1 = q0 + 16 + lr;

    const _Float16* qn = qk + (size_t)h * L * HD;
    const _Float16* kn = qk + ((size_t)(NH + h) * L) * HD;
    const _Float16* vp = vt + (size_t)h * HD * L;

    half8 qa[2][4];
#pragma unroll
    for (int g = 0; g < 2; g++)
#pragma unroll
        for (int kk = 0; kk < 4; kk++)
            qa[g][kk] = *reinterpret_cast<const half8*>(
                qn + (size_t)(q0 + g * 16 + lr) * HD + kk * 32 + lg * 8);

    f32x4 oacc[2][8];
#pragma unroll
    for (int g = 0; g < 2; g++)
#pragma unroll
        for (int jo = 0; jo < 8; jo++) oacc[g][jo] = (f32x4){0.f, 0.f, 0.f, 0.f};
    float lsum0 = 0.f, lsum1 = 0.f;

    auto stage_k = [&](int t, int b) {
        const char* src = (const char*)(kn + (size_t)t * 64 * HD) + wid * 4096 + lane * 16;
        char* dst = (char*)&Kt[b][0] + wid * 4096;
#pragma unroll
        for (int i = 0; i < 4; i++)
            gload_lds16(src + i * 1024, dst + i * 1024);
    };
    auto stage_v = [&](int t, int b) {
        const char* vpb = (const char*)vp + (size_t)t * 128;
        char* dst = (char*)&Vt[b][0] + wid * 4096;
        int dbase = wid * 32 + (lane >> 3);
        int colb = (lane & 7) * 16;
#pragma unroll
        for (int i = 0; i < 4; i++)
            gload_lds16(vpb + (size_t)(dbase + i * 8) * (L * 2) + colb, dst + i * 1024);
    };

    if (t0 < t1) {
        stage_k(t0, 0);
        stage_v(t0, 0);

        for (int t = t0; t < t1; t++) {
            int cur = (t - t0) & 1;
            int kv0 = t * 64;
            bool hasnext = (t + 1 < t1);

            asm volatile("s_waitcnt vmcnt(0)" ::: "memory");
            __builtin_amdgcn_sched_barrier(0);

            __builtin_amdgcn_s_barrier();
            __builtin_amdgcn_sched_barrier(0);

            if (hasnext) {
                stage_v(t + 1, cur ^ 1);
                stage_k(t + 1, cur ^ 1);
            }
            __builtin_amdgcn_sched_barrier(0);

            f32x4 sC0[4], sC1[4];
#pragma unroll
            for (int jt = 0; jt < 4; jt++) {
                sC0[jt] = (f32x4){0.f, 0.f, 0.f, 0.f};
                sC1[jt] = (f32x4){0.f, 0.f, 0.f, 0.f};
            }
            const char* kb = (const char*)&Kt[cur][0];
            __builtin_amdgcn_s_setprio(1);
#pragma unroll
            for (int kk = 0; kk < 4; kk++) {
#pragma unroll
                for (int jt = 0; jt < 4; jt++) {
                    half8 bk = *(const half8*)(kb + (jt * 16 + lr) * 256 +
                                               ((kk * 64 + lg * 16) ^ ((lr & 7) << 4)));
                    sC0[jt] = __builtin_amdgcn_mfma_f32_16x16x32_f16(bk, qa[0][kk], sC0[jt], 0, 0, 0);
                    sC1[jt] = __builtin_amdgcn_mfma_f32_16x16x32_f16(bk, qa[1][kk], sC1[jt], 0, 0, 0);
                }
            }
            __builtin_amdgcn_s_setprio(0);

            bool dz = (t >= ntt - 2);
            unsigned pkr0[4][2], pkr1[4][2];
#pragma unroll
            for (int jt = 0; jt < 4; jt++) {
                float pv0[4], pv1[4];
#pragma unroll
                for (int r = 0; r < 4; r++) {
                    int kv = kv0 + jt * 16 + lg * 4 + r;
                    pv0[r] = __expf(sC0[jt][r] * scale - OFF);
                    pv1[r] = __expf(sC1[jt][r] * scale - OFF);
                    if (dz && (kv > qa0)) pv0[r] = 0.f;
                    if (dz && (kv > qa1)) pv1[r] = 0.f;
                    lsum0 += pv0[r];
                    lsum1 += pv1[r];
                }
                pkr0[jt][0] = pkrtz_u32(pv0[0], pv0[1]);
                pkr0[jt][1] = pkrtz_u32(pv0[2], pv0[3]);
                pkr1[jt][0] = pkrtz_u32(pv1[0], pv1[1]);
                pkr1[jt][1] = pkrtz_u32(pv1[2], pv1[3]);
            }

            const char* vb = (const char*)&Vt[cur][0];
            __builtin_amdgcn_s_setprio(1);
#pragma unroll
            for (int kk2 = 0; kk2 < 2; kk2++) {
                union { unsigned u[4]; half8 h; } pa0, pa1;
#pragma unroll
                for (int c = 0; c < 4; c++) {
                    int src = lr + 16 * ((lg & 1) * 2 + (c >> 1));
                    unsigned va0 = __shfl(pkr0[2 * kk2][c & 1], src);
                    unsigned vb0 = __shfl(pkr0[2 * kk2 + 1][c & 1], src);
                    pa0.u[c] = (lg < 2) ? va0 : vb0;
                    unsigned va1 = __shfl(pkr1[2 * kk2][c & 1], src);
                    unsigned vb1 = __shfl(pkr1[2 * kk2 + 1][c & 1], src);
                    pa1.u[c] = (lg < 2) ? va1 : vb1;
                }
#pragma unroll
                for (int jo = 0; jo < 8; jo++) {
                    int row = jo * 16 + lr;
                    half8 bv = *(const half8*)(vb + row * 128 +
                                               ((kk2 * 64 + lg * 16) ^ ((row & 7) << 4)));
                    oacc[0][jo] = __builtin_amdgcn_mfma_f32_16x16x32_f16(pa0.h, bv, oacc[0][jo], 0, 0, 0);
                    oacc[1][jo] = __builtin_amdgcn_mfma_f32_16x16x32_f16(pa1.h, bv, oacc[1][jo], 0, 0, 0);
                }
            }
            __builtin_amdgcn_s_setprio(0);
        }
    }

    lsum0 += __shfl_xor(lsum0, 16);
    lsum0 += __shfl_xor(lsum0, 32);
    lsum1 += __shfl_xor(lsum1, 16);
    lsum1 += __shfl_xor(lsum1, 32);
    if (lane < 16) {
        Lq[((size_t)p * NH + h) * L + q0 + lr] = lsum0;
        Lq[((size_t)p * NH + h) * L + q0 + 16 + lr] = lsum1;
    }

    _Float16* ob = Oq + (size_t)p * L * D;
#pragma unroll
    for (int g = 0; g < 2; g++) {
#pragma unroll
        for (int jo = 0; jo < 8; jo++) {
#pragma unroll
            for (int r = 0; r < 4; r++) {
                int row = q0 + g * 16 + lg * 4 + r;
                int col = h * HD + jo * 16 + lr;
                ob[(size_t)row * D + col] = (_Float16)oacc[g][jo][r];
            }
        }
    }
}

// ---------------- normalize: aoh = fp16(sum_q Oq / sum_q Lq) ----------------
__global__ void normalize_o(const _Float16* __restrict__ Oq, const float* __restrict__ Lq,
                            _Float16* __restrict__ out) {
    int i8 = blockIdx.x * blockDim.x + threadIdx.x;   // over L*D/8
    int row = i8 >> 8;                                 // D/8 = 256
    int c8 = (i8 & 255) << 3;
    int h = c8 >> 7;
    const size_t QS = (size_t)L * D / 8;
    half8 a0 = reinterpret_cast<const half8*>(Oq)[i8];
    half8 a1 = reinterpret_cast<const half8*>(Oq)[QS + i8];
    half8 a2 = reinterpret_cast<const half8*>(Oq)[2 * QS + i8];
    half8 a3 = reinterpret_cast<const half8*>(Oq)[3 * QS + i8];
    float l = Lq[(size_t)h * L + row] + Lq[((size_t)NH + h) * L + row] +
              Lq[((size_t)2 * NH + h) * L + row] + Lq[((size_t)3 * NH + h) * L + row];
    float inv = 1.0f / l;
    half8 o;
#pragma unroll
    for (int j = 0; j < 8; j++)
        o[j] = (_Float16)(((float)a0[j] + (float)a1[j] + (float)a2[j] + (float)a3[j]) * inv);
    reinterpret_cast<half8*>(out)[i8] = o;
}

extern "C" void kernel_launch(void* const* d_in, const int* in_sizes, int n_in,
                              void* d_out, int out_size, void* d_ws, size_t ws_size,
                              hipStream_t stream) {
    const float* x = (const float*)d_in[0];
    const float* wqkv = (const float*)d_in[1];
    const float* wout = (const float*)d_in[2];
    // block_mask (d_in[3]) is tril(ones) == causal; handled analytically.

    _Float16* ws = (_Float16*)d_ws;
    _Float16* xh = ws;                                    // L*D      (dead after gemm)
    _Float16* wqkvh = xh + (size_t)L * D;                 // 3*D*D    (dead after gemm)
    _Float16* wouth = wqkvh + (size_t)3 * D * D;          // D*D      (live to end)
    _Float16* qkh = wouth + (size_t)D * D;                // 2*L*D    (dead after attn)
    _Float16* vth = qkh + (size_t)2 * NH * L * HD;        // L*D      (dead after attn)
    float* Lq = (float*)(vth + (size_t)L * D);            // 4*NH*L f32
    // aliases into dead regions:
    _Float16* Oq = xh;                                    // 4*L*D partials over xh+wqkvh
    _Float16* aoh = qkh;                                  // L*D over dead qkh

    cvt3_kernel<<<2048, 256, 0, stream>>>(x, wqkv, wout, xh, wqkvh, wouth,
                                          L * D / 4, 3 * D * D / 4, D * D / 4);

    gemm_qkv<<<dim3(L / 128, 3 * D / 64), 256, 0, stream>>>(
        xh, wqkvh, qkh, vth, L, 3 * D, D);

    norm_rope<<<2 * NH * L / 16, 256, 0, stream>>>(qkh);

    attn_kernel<<<1024, 256, 0, stream>>>(qkh, vth, Oq, Lq);

    normalize_o<<<L * D / 8 / 256, 256, 0, stream>>>(Oq, Lq, aoh);

    gemm_out<<<dim3(L / 64, D / 128), 256, 0, stream>>>(
        aoh, wouth, (float*)d_out, L, D, D);
}

// Round 25
// 174.625 us; speedup vs baseline: 1.1652x; 1.1652x over previous
//
#include <hip/hip_runtime.h>

#define L 2048
#define D 2048
#define NH 16
#define HD 128

typedef __attribute__((ext_vector_type(8))) _Float16 half8;
typedef __attribute__((ext_vector_type(4))) float f32x4;

__device__ __forceinline__ void gload_lds16(const void* g, void* l) {
    __builtin_amdgcn_global_load_lds(
        (const __attribute__((address_space(1))) uint32_t*)g,
        (__attribute__((address_space(3))) uint32_t*)l, 16, 0, 0);
}

// pack two f32 -> fp16x2 (RTZ), return as u32
__device__ __forceinline__ unsigned pkrtz_u32(float a, float b) {
    union { __fp16 __attribute__((ext_vector_type(2))) h; unsigned u; } c;
    c.h = __builtin_amdgcn_cvt_pkrtz(a, b);
    return c.u;
}

// ---------------- fused f32 -> fp16 convert of x, W_qkv, W_out ----------------
__global__ void cvt3_kernel(const float* __restrict__ a, const float* __restrict__ b,
                            const float* __restrict__ c, _Float16* __restrict__ oa,
                            _Float16* __restrict__ ob, _Float16* __restrict__ oc,
                            int na, int nb, int nc) {
    int idx = blockIdx.x * blockDim.x + threadIdx.x;
    int stride = gridDim.x * blockDim.x;
    int ntot = na + nb + nc;
    for (int i = idx; i < ntot; i += stride) {
        const float* src; _Float16* dst; int j;
        if (i < na)            { src = a; dst = oa; j = i; }
        else if (i < na + nb)  { src = b; dst = ob; j = i - na; }
        else                   { src = c; dst = oc; j = i - na - nb; }
        float4 v = reinterpret_cast<const float4*>(src)[j];
        union { _Float16 h[4]; uint2 u; } pk;
        pk.h[0] = (_Float16)v.x; pk.h[1] = (_Float16)v.y;
        pk.h[2] = (_Float16)v.z; pk.h[3] = (_Float16)v.w;
        reinterpret_cast<uint2*>(dst)[j] = pk.u;
    }
}

// ---------------- NT GEMM (QKV): C[M][N] = A[M][K] * B[N][K]^T ----------------
// 128x128 tile, 2-buffer drain loop: the measured optimum of this template.
// Tile-size bracket complete: 128x64=105us, 128^2=73us, 256^2=85us.
// Escapes measured as regressions: T1 swizzle (+10%), triple-buffer (+12%),
// fused norm epilogue (spill, 6x). 73us/706TF ~= 80% of m97 ceiling.
// Epilogue scatters qkv: q -> qk[0][h][l][d] linear;
//   k -> qk[1][h][l][d^((l&7)<<3)]; v -> vt[h][d][l^((d&7)<<3)].
__global__ __launch_bounds__(256) void gemm_nt(
    const _Float16* __restrict__ A, const _Float16* __restrict__ B,
    _Float16* __restrict__ qk, _Float16* __restrict__ vt,
    int M, int N, int K)
{
    __shared__ __align__(16) _Float16 Asm[2][128 * 32];   // 2 x 8 KB
    __shared__ __align__(16) _Float16 Bsm[2][128 * 32];   // 2 x 8 KB
    int tid = threadIdx.x;
    int wid = tid >> 6;
    int lane = tid & 63;
    int wr = wid >> 1, wc = wid & 1;
    int m0 = blockIdx.x * 128;
    int n0 = blockIdx.y * 128;
    int lr = lane & 15;
    int lg = lane >> 4;

    const char* Asrc = (const char*)(A + (size_t)(m0 + (tid >> 2)) * K) + (tid & 3) * 16;
    const char* Bsrc = (const char*)(B + (size_t)(n0 + (tid >> 2)) * K) + (tid & 3) * 16;
    size_t rowskip = (size_t)64 * K * 2;

    auto stage = [&](int k0, int b) {
        const char* as = Asrc + (size_t)k0 * 2;
        const char* bs = Bsrc + (size_t)k0 * 2;
        char* ad = (char*)&Asm[b][0] + wid * 1024;
        char* bd = (char*)&Bsm[b][0] + wid * 1024;
        gload_lds16(as, ad);
        gload_lds16(as + rowskip, ad + 4096);
        gload_lds16(bs, bd);
        gload_lds16(bs + rowskip, bd + 4096);
    };

    f32x4 acc[4][4];
#pragma unroll
    for (int i = 0; i < 4; i++)
#pragma unroll
        for (int j = 0; j < 4; j++)
            acc[i][j] = (f32x4){0.f, 0.f, 0.f, 0.f};

    int NT = K / 32;
    stage(0, 0);
    asm volatile("s_waitcnt vmcnt(0)" ::: "memory");
    __syncthreads();

    for (int t = 0; t < NT; t++) {
        int cur = t & 1;
        if (t + 1 < NT) stage((t + 1) * 32, cur ^ 1);

        const char* ab = (const char*)&Asm[cur][0] + (wr * 64 + lr) * 64 + lg * 16;
        const char* bb = (const char*)&Bsm[cur][0] + (wc * 64 + lr) * 64 + lg * 16;
        half8 a[4], b[4];
#pragma unroll
        for (int i = 0; i < 4; i++) a[i] = *(const half8*)(ab + i * 1024);
#pragma unroll
        for (int j = 0; j < 4; j++) b[j] = *(const half8*)(bb + j * 1024);
#pragma unroll
        for (int i = 0; i < 4; i++)
#pragma unroll
            for (int j = 0; j < 4; j++)
                acc[i][j] = __builtin_amdgcn_mfma_f32_16x16x32_f16(a[i], b[j], acc[i][j], 0, 0, 0);

        asm volatile("s_waitcnt vmcnt(0)" ::: "memory");
        __syncthreads();
    }

#pragma unroll
    for (int i = 0; i < 4; i++) {
#pragma unroll
        for (int j = 0; j < 4; j++) {
#pragma unroll
            for (int r = 0; r < 4; r++) {
                int row = m0 + wr * 64 + i * 16 + lg * 4 + r;
                int col = n0 + wc * 64 + j * 16 + lr;
                float v = acc[i][j][r];
                int t = col >> 11;
                int w2 = col & 2047;
                int h = w2 >> 7, d = w2 & 127;
                if (t == 0) {
                    qk[(((size_t)h) * L + row) * HD + d] = (_Float16)v;
                } else if (t == 1) {
                    int dsw = d ^ ((row & 7) << 3);
                    qk[(((size_t)NH + h) * L + row) * HD + dsw] = (_Float16)v;
                } else {
                    int lsw = row ^ ((d & 7) << 3);
                    vt[((size_t)h * HD + d) * L + lsw] = (_Float16)v;
                }
            }
        }
    }
}

// ---------------- output-projection GEMM ----------------
// 64x128 tile -> 512 blocks = 2 blocks/CU (r17: helped vs 1/CU).
__global__ __launch_bounds__(256) void gemm_out(
    const _Float16* __restrict__ A, const _Float16* __restrict__ B,
    float* __restrict__ Cout, int M, int N, int K)
{
    __shared__ __align__(16) _Float16 Asm[2][64 * 32];
    __shared__ __align__(16) _Float16 Bsm[2][128 * 32];
    int tid = threadIdx.x;
    int wid = tid >> 6;
    int lane = tid & 63;
    int m0 = blockIdx.x * 64;
    int n0 = blockIdx.y * 128;
    int lr = lane & 15;
    int lg = lane >> 4;

    const char* Asrc = (const char*)(A + (size_t)(m0 + (tid >> 2)) * K) + (tid & 3) * 16;
    const char* Bsrc = (const char*)(B + (size_t)(n0 + (tid >> 2)) * K) + (tid & 3) * 16;
    size_t rowskip = (size_t)64 * K * 2;

    auto stage = [&](int k0, int b) {
        const char* as = Asrc + (size_t)k0 * 2;
        const char* bs = Bsrc + (size_t)k0 * 2;
        char* ad = (char*)&Asm[b][0] + wid * 1024;
        char* bd = (char*)&Bsm[b][0] + wid * 1024;
        gload_lds16(as, ad);
        gload_lds16(bs, bd);
        gload_lds16(bs + rowskip, bd + 4096);
    };

    f32x4 acc[4][2];
#pragma unroll
    for (int i = 0; i < 4; i++)
#pragma unroll
        for (int j = 0; j < 2; j++)
            acc[i][j] = (f32x4){0.f, 0.f, 0.f, 0.f};

    int NT = K / 32;
    stage(0, 0);
    asm volatile("s_waitcnt vmcnt(0)" ::: "memory");
    __syncthreads();

    for (int t = 0; t < NT; t++) {
        int cur = t & 1;
        if (t + 1 < NT) stage((t + 1) * 32, cur ^ 1);

        const char* ab = (const char*)&Asm[cur][0] + lr * 64 + lg * 16;
        const char* bb = (const char*)&Bsm[cur][0] + (wid * 32 + lr) * 64 + lg * 16;
        half8 a[4], b[2];
#pragma unroll
        for (int i = 0; i < 4; i++) a[i] = *(const half8*)(ab + i * 1024);
#pragma unroll
        for (int j = 0; j < 2; j++) b[j] = *(const half8*)(bb + j * 1024);
#pragma unroll
        for (int i = 0; i < 4; i++)
#pragma unroll
            for (int j = 0; j < 2; j++)
                acc[i][j] = __builtin_amdgcn_mfma_f32_16x16x32_f16(a[i], b[j], acc[i][j], 0, 0, 0);

        asm volatile("s_waitcnt vmcnt(0)" ::: "memory");
        __syncthreads();
    }

#pragma unroll
    for (int i = 0; i < 4; i++) {
#pragma unroll
        for (int j = 0; j < 2; j++) {
#pragma unroll
            for (int r = 0; r < 4; r++) {
                int row = m0 + i * 16 + lg * 4 + r;
                int col = n0 + wid * 32 + j * 16 + lr;
                Cout[(size_t)row * N + col] = acc[i][j][r];
            }
        }
    }
}

// ---------------- fused RMSNorm + RoPE, v2: vectorized (G13) ----------------
__global__ void norm_rope(_Float16* __restrict__ qk) {
    int row = blockIdx.x * 16 + (threadIdx.x >> 4);   // 0 .. 2*NH*L-1
    int lane16 = threadIdx.x & 15;
    int l = row & (L - 1);
    int th = row >> 11;                  // t*NH + h, 0..31
    _Float16* p = qk + ((size_t)th * L + l) * HD + lane16 * 8;
    half8 v = *reinterpret_cast<const half8*>(p);
    float f[8];
    float ss = 0.f;
#pragma unroll
    for (int j = 0; j < 8; j++) { f[j] = (float)v[j]; ss += f[j] * f[j]; }
#pragma unroll
    for (int off = 1; off < 16; off <<= 1) ss += __shfl_xor(ss, off);
    float rinv = rsqrtf(ss * (1.0f / 128.0f) + 1e-5f);

    int dbase = (th >= NH) ? ((lane16 * 8) ^ ((l & 7) << 3)) : (lane16 * 8);
    int p0 = dbase >> 1;                 // first pair index of this lane's block
    half8 o;
#pragma unroll
    for (int k = 0; k < 4; k++) {
        float e = f[2 * k] * rinv;       // t_even (d = 2p)
        float od = f[2 * k + 1] * rinv;  // t_odd  (d = 2p+1)
        float freq = __expf(-0.17988946f * (float)(p0 + k));   // 2*ln(1e5)/128
        float sv, cv;
        __sincosf((float)l * freq, &sv, &cv);
        o[2 * k] = (_Float16)(od * cv - e * sv);
        o[2 * k + 1] = (_Float16)(od * sv + e * cv);
    }
    *reinterpret_cast<half8*>(p) = o;
}

// ---------------- causal flash attention, v15 (r21-exact) ----------------
__global__ __launch_bounds__(256, 2) void attn_kernel(
    const _Float16* __restrict__ qk, const _Float16* __restrict__ vt,
    _Float16* __restrict__ Oq, float* __restrict__ Lq)
{
    __shared__ __align__(16) _Float16 Kt[2][64 * HD];     // 2 x 16 KB
    __shared__ __align__(16) _Float16 Vt[2][64 * HD];     // 2 x 16 KB
    int wid = threadIdx.x >> 6, lane = threadIdx.x & 63;
    int lr = lane & 15, lg = lane >> 4;

    const float scale = 0.08838834764831845f;  // 1/sqrt(128)
    const float OFF = 4.0f;                    // static exp offset (absolute)

    int item = blockIdx.x;
    int qt = 15 - (item >> 6);
    int h = (item >> 2) & 15;
    int p = item & 3;
    int ntt = 2 * qt + 2;
    int per = (ntt + 3) >> 2;
    int t0 = p * per;
    int t1 = t0 + per < ntt ? t0 + per : ntt;
    int q0 = qt * 128 + wid * 32;
    int qa0 = q0 + lr;
    int qa1 = q0 + 16 + lr;

    const _Float16* qn = qk + (size_t)h * L * HD;
    const _Float16* kn = qk + ((size_t)(NH + h) * L) * HD;
    const _Float16* vp = vt + (size_t)h * HD * L;

    half8 qa[2][4];
#pragma unroll
    for (int g = 0; g < 2; g++)
#pragma unroll
        for (int kk = 0; kk < 4; kk++)
            qa[g][kk] = *reinterpret_cast<const half8*>(
                qn + (size_t)(q0 + g * 16 + lr) * HD + kk * 32 + lg * 8);

    f32x4 oacc[2][8];
#pragma unroll
    for (int g = 0; g < 2; g++)
#pragma unroll
        for (int jo = 0; jo < 8; jo++) oacc[g][jo] = (f32x4){0.f, 0.f, 0.f, 0.f};
    float lsum0 = 0.f, lsum1 = 0.f;

    auto stage_k = [&](int t, int b) {
        const char* src = (const char*)(kn + (size_t)t * 64 * HD) + wid * 4096 + lane * 16;
        char* dst = (char*)&Kt[b][0] + wid * 4096;
#pragma unroll
        for (int i = 0; i < 4; i++)
            gload_lds16(src + i * 1024, dst + i * 1024);
    };
    auto stage_v = [&](int t, int b) {
        const char* vpb = (const char*)vp + (size_t)t * 128;
        char* dst = (char*)&Vt[b][0] + wid * 4096;
        int dbase = wid * 32 + (lane >> 3);
        int colb = (lane & 7) * 16;
#pragma unroll
        for (int i = 0; i < 4; i++)
            gload_lds16(vpb + (size_t)(dbase + i * 8) * (L * 2) + colb, dst + i * 1024);
    };

    if (t0 < t1) {
        stage_k(t0, 0);
        stage_v(t0, 0);

        for (int t = t0; t < t1; t++) {
            int cur = (t - t0) & 1;
            int kv0 = t * 64;
            bool hasnext = (t + 1 < t1);

            asm volatile("s_waitcnt vmcnt(0)" ::: "memory");
            __builtin_amdgcn_sched_barrier(0);

            __builtin_amdgcn_s_barrier();
            __builtin_amdgcn_sched_barrier(0);

            if (hasnext) {
                stage_v(t + 1, cur ^ 1);
                stage_k(t + 1, cur ^ 1);
            }
            __builtin_amdgcn_sched_barrier(0);

            f32x4 sC0[4], sC1[4];
#pragma unroll
            for (int jt = 0; jt < 4; jt++) {
                sC0[jt] = (f32x4){0.f, 0.f, 0.f, 0.f};
                sC1[jt] = (f32x4){0.f, 0.f, 0.f, 0.f};
            }
            const char* kb = (const char*)&Kt[cur][0];
            __builtin_amdgcn_s_setprio(1);
#pragma unroll
            for (int kk = 0; kk < 4; kk++) {
#pragma unroll
                for (int jt = 0; jt < 4; jt++) {
                    half8 bk = *(const half8*)(kb + (jt * 16 + lr) * 256 +
                                               ((kk * 64 + lg * 16) ^ ((lr & 7) << 4)));
                    sC0[jt] = __builtin_amdgcn_mfma_f32_16x16x32_f16(bk, qa[0][kk], sC0[jt], 0, 0, 0);
                    sC1[jt] = __builtin_amdgcn_mfma_f32_16x16x32_f16(bk, qa[1][kk], sC1[jt], 0, 0, 0);
                }
            }
            __builtin_amdgcn_s_setprio(0);

            bool dz = (t >= ntt - 2);
            unsigned pkr0[4][2], pkr1[4][2];
#pragma unroll
            for (int jt = 0; jt < 4; jt++) {
                float pv0[4], pv1[4];
#pragma unroll
                for (int r = 0; r < 4; r++) {
                    int kv = kv0 + jt * 16 + lg * 4 + r;
                    pv0[r] = __expf(sC0[jt][r] * scale - OFF);
                    pv1[r] = __expf(sC1[jt][r] * scale - OFF);
                    if (dz && (kv > qa0)) pv0[r] = 0.f;
                    if (dz && (kv > qa1)) pv1[r] = 0.f;
                    lsum0 += pv0[r];
                    lsum1 += pv1[r];
                }
                pkr0[jt][0] = pkrtz_u32(pv0[0], pv0[1]);
                pkr0[jt][1] = pkrtz_u32(pv0[2], pv0[3]);
                pkr1[jt][0] = pkrtz_u32(pv1[0], pv1[1]);
                pkr1[jt][1] = pkrtz_u32(pv1[2], pv1[3]);
            }

            const char* vb = (const char*)&Vt[cur][0];
            __builtin_amdgcn_s_setprio(1);
#pragma unroll
            for (int kk2 = 0; kk2 < 2; kk2++) {
                union { unsigned u[4]; half8 h; } pa0, pa1;
#pragma unroll
                for (int c = 0; c < 4; c++) {
                    int src = lr + 16 * ((lg & 1) * 2 + (c >> 1));
                    unsigned va0 = __shfl(pkr0[2 * kk2][c & 1], src);
                    unsigned vb0 = __shfl(pkr0[2 * kk2 + 1][c & 1], src);
                    pa0.u[c] = (lg < 2) ? va0 : vb0;
                    unsigned va1 = __shfl(pkr1[2 * kk2][c & 1], src);
                    unsigned vb1 = __shfl(pkr1[2 * kk2 + 1][c & 1], src);
                    pa1.u[c] = (lg < 2) ? va1 : vb1;
                }
#pragma unroll
                for (int jo = 0; jo < 8; jo++) {
                    int row = jo * 16 + lr;
                    half8 bv = *(const half8*)(vb + row * 128 +
                                               ((kk2 * 64 + lg * 16) ^ ((row & 7) << 4)));
                    oacc[0][jo] = __builtin_amdgcn_mfma_f32_16x16x32_f16(pa0.h, bv, oacc[0][jo], 0, 0, 0);
                    oacc[1][jo] = __builtin_amdgcn_mfma_f32_16x16x32_f16(pa1.h, bv, oacc[1][jo], 0, 0, 0);
                }
            }
            __builtin_amdgcn_s_setprio(0);
        }
    }

    lsum0 += __shfl_xor(lsum0, 16);
    lsum0 += __shfl_xor(lsum0, 32);
    lsum1 += __shfl_xor(lsum1, 16);
    lsum1 += __shfl_xor(lsum1, 32);
    if (lane < 16) {
        Lq[((size_t)p * NH + h) * L + q0 + lr] = lsum0;
        Lq[((size_t)p * NH + h) * L + q0 + 16 + lr] = lsum1;
    }

    _Float16* ob = Oq + (size_t)p * L * D;
#pragma unroll
    for (int g = 0; g < 2; g++) {
#pragma unroll
        for (int jo = 0; jo < 8; jo++) {
#pragma unroll
            for (int r = 0; r < 4; r++) {
                int row = q0 + g * 16 + lg * 4 + r;
                int col = h * HD + jo * 16 + lr;
                ob[(size_t)row * D + col] = (_Float16)oacc[g][jo][r];
            }
        }
    }
}

// ---------------- normalize: aoh = fp16(sum_q Oq / sum_q Lq) ----------------
__global__ void normalize_o(const _Float16* __restrict__ Oq, const float* __restrict__ Lq,
                            _Float16* __restrict__ out) {
    int i8 = blockIdx.x * blockDim.x + threadIdx.x;   // over L*D/8
    int row = i8 >> 8;                                 // D/8 = 256
    int c8 = (i8 & 255) << 3;
    int h = c8 >> 7;
    const size_t QS = (size_t)L * D / 8;
    half8 a0 = reinterpret_cast<const half8*>(Oq)[i8];
    half8 a1 = reinterpret_cast<const half8*>(Oq)[QS + i8];
    half8 a2 = reinterpret_cast<const half8*>(Oq)[2 * QS + i8];
    half8 a3 = reinterpret_cast<const half8*>(Oq)[3 * QS + i8];
    float l = Lq[(size_t)h * L + row] + Lq[((size_t)NH + h) * L + row] +
              Lq[((size_t)2 * NH + h) * L + row] + Lq[((size_t)3 * NH + h) * L + row];
    float inv = 1.0f / l;
    half8 o;
#pragma unroll
    for (int j = 0; j < 8; j++)
        o[j] = (_Float16)(((float)a0[j] + (float)a1[j] + (float)a2[j] + (float)a3[j]) * inv);
    reinterpret_cast<half8*>(out)[i8] = o;
}

extern "C" void kernel_launch(void* const* d_in, const int* in_sizes, int n_in,
                              void* d_out, int out_size, void* d_ws, size_t ws_size,
                              hipStream_t stream) {
    const float* x = (const float*)d_in[0];
    const float* wqkv = (const float*)d_in[1];
    const float* wout = (const float*)d_in[2];
    // block_mask (d_in[3]) is tril(ones) == causal; handled analytically.

    _Float16* ws = (_Float16*)d_ws;
    _Float16* xh = ws;                                    // L*D      (dead after gemm)
    _Float16* wqkvh = xh + (size_t)L * D;                 // 3*D*D    (dead after gemm)
    _Float16* wouth = wqkvh + (size_t)3 * D * D;          // D*D      (live to end)
    _Float16* qkh = wouth + (size_t)D * D;                // 2*L*D    (dead after attn)
    _Float16* vth = qkh + (size_t)2 * NH * L * HD;        // L*D      (dead after attn)
    float* Lq = (float*)(vth + (size_t)L * D);            // 4*NH*L f32
    // aliases into dead regions:
    _Float16* Oq = xh;                                    // 4*L*D partials over xh+wqkvh
    _Float16* aoh = qkh;                                  // L*D over dead qkh

    cvt3_kernel<<<2048, 256, 0, stream>>>(x, wqkv, wout, xh, wqkvh, wouth,
                                          L * D / 4, 3 * D * D / 4, D * D / 4);

    gemm_nt<<<dim3(L / 128, 3 * D / 128), 256, 0, stream>>>(
        xh, wqkvh, qkh, vth, L, 3 * D, D);

    norm_rope<<<2 * NH * L / 16, 256, 0, stream>>>(qkh);

    attn_kernel<<<1024, 256, 0, stream>>>(qkh, vth, Oq, Lq);

    normalize_o<<<L * D / 8 / 256, 256, 0, stream>>>(Oq, Lq, aoh);

    gemm_out<<<dim3(L / 64, D / 128), 256, 0, stream>>>(
        aoh, wouth, (float*)d_out, L, D, D);
}